// Round 5
// baseline (735.468 us; speedup 1.0000x reference)
//
#include <hip/hip_runtime.h>
#include <hip/hip_bf16.h>
#include <math.h>

#define C_DIM 2048
#define E_DIM 64
#define KC 64
#define NCHUNK 32          // 2048 / 64
#define FOLD_EVERY 6       // 6 chunks * 64 = 384 = OpenBLAS sgemm kc (FROZEN: round-4 pass)

// ===========================================================================
// FROZEN ARITHMETIC (validated round 4, absmax 2.4e-4):
//  - norms: numpy pairwise tree over 16 base-blocks of 128 (8 accs x 16
//    sequential adds, ((r0+r1)+(r2+r3))+((r4+r5)+(r6+r7)), perfect binary
//    tree over consecutive blocks), x*x rounded separately (__fmul_rn).
//  - normalize: IEEE fp32 divide per element.
//  - dot: per (row,expert) single fp32 acc, sequential fmaf ascending k,
//    kc=384 partials folded in order ((((p0+p1)+p2)+p3)+p4)+p5.
// Only ACCESS PATTERNS change in this round, never bracketing.
// ===========================================================================

// ---------------------------------------------------------------------------
// xnorm v2: 2 rows per wave, all-float4 loads.
// Lane (l>>5)=row-half owns block b=(l&31)>>1 (of 16x128), acc-quad
// a=(l&1)*4. float4 at [b*128 + p*8 + a] = accs a..a+3 at position p ->
// component-wise accumulate over p=0..15 IS the 8-acc base case.
// Butterfly xor 1,2,4,8,16 = in-order perfect tree over accs/blocks.
// ---------------------------------------------------------------------------
__global__ __launch_bounds__(256) void xnorm_kernel(const float* __restrict__ X,
                                                    float* __restrict__ den, int N) {
  const int w = threadIdx.x >> 6, l = threadIdx.x & 63;
  const int row = blockIdx.x * 8 + w * 2 + (l >> 5);
  const int task = l & 31;
  const int b = task >> 1, a = (task & 1) * 4;
  const float* p0 = X + (size_t)row * C_DIM + b * 128 + a;

  float4 v = *(const float4*)p0;
  float ax = __fmul_rn(v.x, v.x), ay = __fmul_rn(v.y, v.y);
  float az = __fmul_rn(v.z, v.z), aw = __fmul_rn(v.w, v.w);
#pragma unroll
  for (int p = 1; p < 16; ++p) {
    v = *(const float4*)(p0 + p * 8);
    ax = __fadd_rn(ax, __fmul_rn(v.x, v.x));
    ay = __fadd_rn(ay, __fmul_rn(v.y, v.y));
    az = __fadd_rn(az, __fmul_rn(v.z, v.z));
    aw = __fadd_rn(aw, __fmul_rn(v.w, v.w));
  }
  // in-lane: (r_a + r_a+1) + (r_a+2 + r_a+3)
  float r = __fadd_rn(__fadd_rn(ax, ay), __fadd_rn(az, aw));
  // xor1: a=0 lane gets ((r0+r1)+(r2+r3)) + ((r4+r5)+(r6+r7)) = block sum
  r = __fadd_rn(r, __shfl_xor(r, 1));
  // xor2,4,8,16: perfect binary tree over blocks 0..15 (root = halves)
  r = __fadd_rn(r, __shfl_xor(r, 2));
  r = __fadd_rn(r, __shfl_xor(r, 4));
  r = __fadd_rn(r, __shfl_xor(r, 8));
  r = __fadd_rn(r, __shfl_xor(r, 16));
  if (task == 0 && row < N) den[row] = fmaxf(sqrtf(r), 1e-12f);
}

// ---------------------------------------------------------------------------
// simnorm_a: per c-base-block (16 blocks of 128 rows) column partial sums.
// One wave per block; lane = column e; 8 named accumulators, sequential c.
// Coalesced: each instruction reads one full 256B row of sim.
// ---------------------------------------------------------------------------
__global__ __launch_bounds__(64) void simnorm_a_kernel(const float* __restrict__ sim,
                                                       float* __restrict__ Bsum) {
  const int b = blockIdx.x, l = threadIdx.x;
  const float* base = sim + (size_t)(b * 128) * E_DIM + l;
#define SQ(c) __fmul_rn(base[(c) * E_DIM], base[(c) * E_DIM])
  float a0 = SQ(0), a1 = SQ(1), a2 = SQ(2), a3 = SQ(3);
  float a4 = SQ(4), a5 = SQ(5), a6 = SQ(6), a7 = SQ(7);
#pragma unroll
  for (int g = 1; g < 16; ++g) {
    a0 = __fadd_rn(a0, SQ(g * 8 + 0)); a1 = __fadd_rn(a1, SQ(g * 8 + 1));
    a2 = __fadd_rn(a2, SQ(g * 8 + 2)); a3 = __fadd_rn(a3, SQ(g * 8 + 3));
    a4 = __fadd_rn(a4, SQ(g * 8 + 4)); a5 = __fadd_rn(a5, SQ(g * 8 + 5));
    a6 = __fadd_rn(a6, SQ(g * 8 + 6)); a7 = __fadd_rn(a7, SQ(g * 8 + 7));
  }
#undef SQ
  const float left = __fadd_rn(__fadd_rn(a0, a1), __fadd_rn(a2, a3));
  const float right = __fadd_rn(__fadd_rn(a4, a5), __fadd_rn(a6, a7));
  Bsum[b * E_DIM + l] = __fadd_rn(left, right);
}

// simnorm_b: fold the 16 block partials (exact tree), write sT[e][c]=sim[c][e]/den.
__global__ __launch_bounds__(256) void simnorm_b_kernel(const float* __restrict__ sim,
                                                        const float* __restrict__ Bsum,
                                                        float* __restrict__ sT) {
  const int e = blockIdx.x, t = threadIdx.x;
  float B[16];
#pragma unroll
  for (int b = 0; b < 16; ++b) B[b] = Bsum[b * E_DIM + e];
  float c01 = __fadd_rn(B[0], B[1]), c23 = __fadd_rn(B[2], B[3]);
  float c45 = __fadd_rn(B[4], B[5]), c67 = __fadd_rn(B[6], B[7]);
  float c89 = __fadd_rn(B[8], B[9]), cab = __fadd_rn(B[10], B[11]);
  float ccd = __fadd_rn(B[12], B[13]), cef = __fadd_rn(B[14], B[15]);
  float q0 = __fadd_rn(c01, c23), q1 = __fadd_rn(c45, c67);
  float q2 = __fadd_rn(c89, cab), q3 = __fadd_rn(ccd, cef);
  const float tot = __fadd_rn(__fadd_rn(q0, q1), __fadd_rn(q2, q3));
  const float den = fmaxf(sqrtf(tot), 1e-12f);
#pragma unroll
  for (int i = 0; i < 8; ++i) {
    const int c = t + i * 256;
    sT[(size_t)e * C_DIM + c] = sim[(size_t)c * E_DIM + e] / den;
  }
}

// ---------------------------------------------------------------------------
// gating_main v2: block = 64 rows x 64 experts, grid 256 (1/CU).
// X: reg-staged (global float4 -> IEEE divide -> ds_write_b128), double-
//    buffered LDS 2x16KB, KC=64. XOR-16 swizzle: phys slot = u ^ ((row>>2)&15)
//    applied on the global source and on the read address (linear LDS).
// sT: per-lane direct global loads (512 KB, L2/L3-resident; 8x duplication
//    rides the TA/L2 pipe, off the LDS port). LDS-port traffic halves vs r4.
// No manual waitcnt: all loads are register loads with compiler-exact deps.
// ---------------------------------------------------------------------------
__global__ __launch_bounds__(256, 1) void gating_main(const float* __restrict__ X,
                                                      const float* __restrict__ denx,
                                                      const float* __restrict__ sT,
                                                      const float* __restrict__ gates,
                                                      const int* __restrict__ fbk,
                                                      float* __restrict__ out, int N) {
  __shared__ float smem[8192];  // 2 bufs x (64 rows x 64 floats) = 32 KB
  const int t = threadIdx.x;
  const int w = t >> 6, l = t & 63;
  const int wr = w >> 1, we = w & 1;   // wave grid: row-half x expert-half
  const int rg = l >> 3, eg = l & 7;   // lane grid: 8 row-groups x 8 expert-groups
  const size_t rowbase = (size_t)blockIdx.x * 64;
  const float* Xb = X + rowbase * C_DIM;

  // staging geometry: 4 units of 16B per thread; unit u' = t + 256*it
  int skidx[4];
  float sden[4];
  const float* sgsrc[4];
#pragma unroll
  for (int it = 0; it < 4; ++it) {
    const int u = t + 256 * it;
    const int srow = u >> 4, sphys = u & 15;
    skidx[it] = sphys ^ ((srow >> 2) & 15);
    sden[it] = denx[rowbase + srow];
    sgsrc[it] = Xb + (size_t)srow * C_DIM + skidx[it] * 4;
  }

  float4 xr[4];
  auto loadX = [&](int ch) {
#pragma unroll
    for (int it = 0; it < 4; ++it) xr[it] = *(const float4*)(sgsrc[it] + ch * KC);
  };
  auto writeX = [&](int buf) {
#pragma unroll
    for (int it = 0; it < 4; ++it) {
      float4 o;
      o.x = xr[it].x / sden[it]; o.y = xr[it].y / sden[it];
      o.z = xr[it].z / sden[it]; o.w = xr[it].w / sden[it];
      *(float4*)&smem[buf * 4096 + (t + 256 * it) * 4] = o;
    }
  };

  float ab[4][4], tt[4][4];
#pragma unroll
  for (int i = 0; i < 4; ++i)
#pragma unroll
    for (int j = 0; j < 4; ++j) ab[i][j] = 0.f;

  const int swz = (wr * 8 + rg) & 15;  // read-side XOR value (row>>2)&15, i-invariant
  const float* sTj[4];
#pragma unroll
  for (int j = 0; j < 4; ++j) sTj[j] = sT + (size_t)(we * 32 + eg * 4 + j) * C_DIM;

  loadX(0);
  writeX(0);
  __syncthreads();

  for (int ch = 0; ch < NCHUNK; ++ch) {
    if (ch && (ch % FOLD_EVERY) == 0) {  // kc=384 boundary: fold partial (FROZEN order)
#pragma unroll
      for (int i = 0; i < 4; ++i)
#pragma unroll
        for (int j = 0; j < 4; ++j) {
          if (ch == FOLD_EVERY) tt[i][j] = ab[i][j];
          else tt[i][j] = __fadd_rn(tt[i][j], ab[i][j]);
          ab[i][j] = 0.f;
        }
    }
    const int buf = ch & 1;
    if (ch + 1 < NCHUNK) loadX(ch + 1);  // in flight across the u-loop
    const int xbase = buf * 4096;
#pragma unroll
    for (int u = 0; u < 16; ++u) {
      float4 xv[4], sv[4];
#pragma unroll
      for (int i = 0; i < 4; ++i) {
        const int row = wr * 32 + rg * 4 + i;
        xv[i] = *(const float4*)&smem[xbase + row * 64 + ((u ^ swz) * 4)];
      }
#pragma unroll
      for (int j = 0; j < 4; ++j)
        sv[j] = *(const float4*)(sTj[j] + ch * KC + u * 4);
#pragma unroll
      for (int i = 0; i < 4; ++i)
#pragma unroll
        for (int j = 0; j < 4; ++j) {  // strict ascending-k fmaf chain (FROZEN)
          float a = ab[i][j];
          a = fmaf(xv[i].x, sv[j].x, a);
          a = fmaf(xv[i].y, sv[j].y, a);
          a = fmaf(xv[i].z, sv[j].z, a);
          a = fmaf(xv[i].w, sv[j].w, a);
          ab[i][j] = a;
        }
    }
    if (ch + 1 < NCHUNK) writeX(buf ^ 1);  // next buf: safe, current reads hit buf
    __syncthreads();
  }
#pragma unroll
  for (int i = 0; i < 4; ++i)
#pragma unroll
    for (int j = 0; j < 4; ++j) tt[i][j] = __fadd_rn(tt[i][j], ab[i][j]);  // tail 128

  // ---- epilogue: logits -> LDS transpose, then per-row wave ops ----
  float* lg = smem;  // [64][66], stride 66 => conflict-free row reads
#pragma unroll
  for (int i = 0; i < 4; ++i) {
    const int row = wr * 32 + rg * 4 + i;
#pragma unroll
    for (int j = 0; j < 4; ++j) lg[row * 66 + we * 32 + eg * 4 + j] = tt[i][j];
  }
  __syncthreads();

  const int k = fbk[0];
  const float gate = gates[l];
  const size_t NE = (size_t)N * E_DIM;

  for (int rr = 0; rr < 16; ++rr) {
    const int row = w * 16 + rr;  // each wave owns 16 rows; lane = expert
    const float logit = __fadd_rn(lg[row * 66 + l], -gate);
    const float gated = fmaxf(logit, 0.f);
    const bool act = logit > 0.f;
    const unsigned long long bal = __ballot(act);
    const bool inactive = (bal == 0ull);

    // top-k of raw logits (tie -> lowest index, matching lax.top_k)
    float cur = logit;
    bool fb = false;
    for (int tk = 0; tk < k; ++tk) {
      float v2 = cur;
      int idx = l;
#pragma unroll
      for (int off = 32; off >= 1; off >>= 1) {
        const float ov = __shfl_xor(v2, off);
        const int oi = __shfl_xor(idx, off);
        if (ov > v2 || (ov == v2 && oi < idx)) { v2 = ov; idx = oi; }
      }
      if (l == idx) { cur = -INFINITY; fb = true; }
    }

    const float mask = inactive ? (fb ? 1.f : 0.f) : (act ? 1.f : 0.f);
    const float masked = (mask > 0.f) ? gated : -INFINITY;
    float m = masked;
#pragma unroll
    for (int off = 32; off >= 1; off >>= 1) m = fmaxf(m, __shfl_xor(m, off));
    const float p = (mask > 0.f) ? expf(masked - m) : 0.f;
    float s = p;
#pragma unroll
    for (int off = 32; off >= 1; off >>= 1) s += __shfl_xor(s, off);
    const float wgt = p / s;

    const size_t gr = rowbase + row;
    out[gr * E_DIM + l] = wgt;             // routing_weights
    out[NE + gr * E_DIM + l] = logit;      // logits
    out[2 * NE + gr * E_DIM + l] = mask;   // activation_mask
  }
}

extern "C" void kernel_launch(void* const* d_in, const int* in_sizes, int n_in,
                              void* d_out, int out_size, void* d_ws, size_t ws_size,
                              hipStream_t stream) {
  (void)n_in; (void)out_size; (void)ws_size;
  const float* X = (const float*)d_in[0];
  const float* sim = (const float*)d_in[1];
  const float* gates = (const float*)d_in[2];
  const int* fbk = (const int*)d_in[3];
  float* out = (float*)d_out;
  float* den = (float*)d_ws;                       // 16384 fp32 = 64 KB
  float* sT = (float*)d_ws + 16384;                // 64*2048 fp32 = 512 KB
  float* Bsum = (float*)d_ws + 16384 + 131072;     // 16*64 fp32 = 4 KB
  const int N = in_sizes[0] / C_DIM;               // 16384

  hipLaunchKernelGGL(xnorm_kernel, dim3(N / 8), dim3(256), 0, stream, X, den, N);
  hipLaunchKernelGGL(simnorm_a_kernel, dim3(16), dim3(64), 0, stream, sim, Bsum);
  hipLaunchKernelGGL(simnorm_b_kernel, dim3(E_DIM), dim3(256), 0, stream, sim, Bsum, sT);
  hipLaunchKernelGGL(gating_main, dim3(N / 64), dim3(256), 0, stream, X, den, sT, gates, fbk, out, N);
}

// Round 8
// 353.239 us; speedup vs baseline: 2.0821x; 2.0821x over previous
//
#include <hip/hip_runtime.h>
#include <hip/hip_bf16.h>
#include <math.h>

#define C_DIM 2048
#define E_DIM 64
#define KC 32
#define NCHUNK 64          // 2048 / 32
#define KC_BLK 12          // 12 chunks * 32 = 384 = OpenBLAS sgemm kc (FROZEN: round-4 pass)

typedef __attribute__((address_space(3))) float lds_f;
typedef const __attribute__((address_space(1))) float glb_f;

// ===========================================================================
// FROZEN ARITHMETIC (validated round 4, absmax 2.4e-4):
//  - norms: numpy pairwise tree (16 base-blocks of 128; 8 accs x 16 sequential
//    adds; ((r0+r1)+(r2+r3))+((r4+r5)+(r6+r7)); perfect tree over blocks),
//    x*x rounded separately (__fmul_rn / __fadd_rn).
//  - normalize: IEEE fp32 divide per element.
//  - dot: per (row,expert) single fp32 acc, sequential fmaf ascending k,
//    kc=384 partials folded in order (((p0+p1)+p2)+p3)+p4)+p5.
// Round 6/7 change ONLY tiling/occupancy (32-row blocks), never bracketing.
// Round-5 lesson: no global loads inside the unrolled u-loop (spill: VGPR 256,
// WRITE_SIZE 608MB); operands come from LDS only.
// ===========================================================================

// --------------------------- xnorm (round-5 version) -----------------------
__global__ __launch_bounds__(256) void xnorm_kernel(const float* __restrict__ X,
                                                    float* __restrict__ den, int N) {
  const int w = threadIdx.x >> 6, l = threadIdx.x & 63;
  const int row = blockIdx.x * 8 + w * 2 + (l >> 5);
  const int task = l & 31;
  const int b = task >> 1, a = (task & 1) * 4;
  const float* p0 = X + (size_t)row * C_DIM + b * 128 + a;

  float4 v = *(const float4*)p0;
  float ax = __fmul_rn(v.x, v.x), ay = __fmul_rn(v.y, v.y);
  float az = __fmul_rn(v.z, v.z), aw = __fmul_rn(v.w, v.w);
#pragma unroll
  for (int p = 1; p < 16; ++p) {
    v = *(const float4*)(p0 + p * 8);
    ax = __fadd_rn(ax, __fmul_rn(v.x, v.x));
    ay = __fadd_rn(ay, __fmul_rn(v.y, v.y));
    az = __fadd_rn(az, __fmul_rn(v.z, v.z));
    aw = __fadd_rn(aw, __fmul_rn(v.w, v.w));
  }
  float r = __fadd_rn(__fadd_rn(ax, ay), __fadd_rn(az, aw));
  r = __fadd_rn(r, __shfl_xor(r, 1));
  r = __fadd_rn(r, __shfl_xor(r, 2));
  r = __fadd_rn(r, __shfl_xor(r, 4));
  r = __fadd_rn(r, __shfl_xor(r, 8));
  r = __fadd_rn(r, __shfl_xor(r, 16));
  if (task == 0 && row < N) den[row] = fmaxf(sqrtf(r), 1e-12f);
}

// --------------------- simnorm a/b (round-5 versions) ----------------------
__global__ __launch_bounds__(64) void simnorm_a_kernel(const float* __restrict__ sim,
                                                       float* __restrict__ Bsum) {
  const int b = blockIdx.x, l = threadIdx.x;
  const float* base = sim + (size_t)(b * 128) * E_DIM + l;
#define SQ(c) __fmul_rn(base[(c) * E_DIM], base[(c) * E_DIM])
  float a0 = SQ(0), a1 = SQ(1), a2 = SQ(2), a3 = SQ(3);
  float a4 = SQ(4), a5 = SQ(5), a6 = SQ(6), a7 = SQ(7);
#pragma unroll
  for (int g = 1; g < 16; ++g) {
    a0 = __fadd_rn(a0, SQ(g * 8 + 0)); a1 = __fadd_rn(a1, SQ(g * 8 + 1));
    a2 = __fadd_rn(a2, SQ(g * 8 + 2)); a3 = __fadd_rn(a3, SQ(g * 8 + 3));
    a4 = __fadd_rn(a4, SQ(g * 8 + 4)); a5 = __fadd_rn(a5, SQ(g * 8 + 5));
    a6 = __fadd_rn(a6, SQ(g * 8 + 6)); a7 = __fadd_rn(a7, SQ(g * 8 + 7));
  }
#undef SQ
  const float left = __fadd_rn(__fadd_rn(a0, a1), __fadd_rn(a2, a3));
  const float right = __fadd_rn(__fadd_rn(a4, a5), __fadd_rn(a6, a7));
  Bsum[b * E_DIM + l] = __fadd_rn(left, right);
}

__global__ __launch_bounds__(256) void simnorm_b_kernel(const float* __restrict__ sim,
                                                        const float* __restrict__ Bsum,
                                                        float* __restrict__ sT) {
  const int e = blockIdx.x, t = threadIdx.x;
  float B[16];
#pragma unroll
  for (int b = 0; b < 16; ++b) B[b] = Bsum[b * E_DIM + e];
  float c01 = __fadd_rn(B[0], B[1]), c23 = __fadd_rn(B[2], B[3]);
  float c45 = __fadd_rn(B[4], B[5]), c67 = __fadd_rn(B[6], B[7]);
  float c89 = __fadd_rn(B[8], B[9]), cab = __fadd_rn(B[10], B[11]);
  float ccd = __fadd_rn(B[12], B[13]), cef = __fadd_rn(B[14], B[15]);
  float q0 = __fadd_rn(c01, c23), q1 = __fadd_rn(c45, c67);
  float q2 = __fadd_rn(c89, cab), q3 = __fadd_rn(ccd, cef);
  const float tot = __fadd_rn(__fadd_rn(q0, q1), __fadd_rn(q2, q3));
  const float den = fmaxf(sqrtf(tot), 1e-12f);
#pragma unroll
  for (int i = 0; i < 8; ++i) {
    const int c = t + i * 256;
    sT[(size_t)e * C_DIM + c] = sim[(size_t)c * E_DIM + e] / den;
  }
}

// ---------------------------------------------------------------------------
// gating_main v3: 32 rows x 64 experts per block, 128 threads (2 waves),
// grid 512 -> 2 independent blocks/CU (barrier stalls of one block hide under
// the other). Round-4 proven pipeline: X reg-staged (float4 -> IEEE divide ->
// ds_write_b128), sT via global_load_lds(16B); KC=32 double-buffered; XOR-8
// swizzle on global source + read address (linear LDS dest); prefetch issued
// before compute, drained after. Per-lane tile 4 rows x 4 experts.
// ---------------------------------------------------------------------------
__global__ __launch_bounds__(128) void gating_main(const float* __restrict__ X,
                                                   const float* __restrict__ denx,
                                                   const float* __restrict__ sT,
                                                   const float* __restrict__ gates,
                                                   const int* __restrict__ fbk,
                                                   float* __restrict__ out, int N) {
  __shared__ float smem[6144];  // X: [0,2048) = 2 bufs x 1024; sT: [2048,6144) = 2 bufs x 2048
  const int t = threadIdx.x;          // 0..127
  const int we = t >> 6, l = t & 63;  // wave = expert-half
  const int rg = l >> 3, eg = l & 7;  // 8 row-groups x 8 expert-groups
  const size_t rowbase = (size_t)blockIdx.x * 32;
  const float* Xb = X + rowbase * C_DIM;

  // X staging: 2 units/thread (u, u+128); 256 units = 32 rows x 8 slots
  const int u0 = t, u1 = t + 128;
  const int r0 = u0 >> 3, cb0 = (u0 & 7) ^ ((r0 >> 2) & 7);
  const int r1 = u1 >> 3, cb1 = (u1 & 7) ^ ((r1 >> 2) & 7);
  const float d0 = denx[rowbase + r0];
  const float d1 = denx[rowbase + r1];
  const float* xg0 = Xb + (size_t)r0 * C_DIM + cb0 * 4;
  const float* xg1 = Xb + (size_t)r1 * C_DIM + cb1 * 4;

  // sT staging: 4 units/thread; 512 units = 64 expert-rows x 8 slots
  const float* sg[4];
  int sdst[4];
#pragma unroll
  for (int it = 0; it < 4; ++it) {
    const int v = t + 128 * it;
    const int er = v >> 3, cb = (v & 7) ^ ((er >> 2) & 7);
    sg[it] = sT + (size_t)er * C_DIM + cb * 4;
    sdst[it] = 2048 + v * 4;  // + buf*2048 at issue time
  }

  float4 xr0, xr1;
  auto issueX = [&](int ch) {
    xr0 = *(const float4*)(xg0 + ch * KC);
    xr1 = *(const float4*)(xg1 + ch * KC);
  };
  auto issueS = [&](int buf, int ch) {
#pragma unroll
    for (int it = 0; it < 4; ++it) {
      glb_f* g = (glb_f*)(sg[it] + ch * KC);
      lds_f* d = (lds_f*)&smem[sdst[it] + buf * 2048];
      __builtin_amdgcn_global_load_lds((const __attribute__((address_space(1))) void*)g,
                                       (__attribute__((address_space(3))) void*)d, 16, 0, 0);
    }
  };
  auto writeX = [&](int buf) {  // IEEE divide (FROZEN), then ds_write_b128
    float4 a, b;
    a.x = xr0.x / d0; a.y = xr0.y / d0; a.z = xr0.z / d0; a.w = xr0.w / d0;
    b.x = xr1.x / d1; b.y = xr1.y / d1; b.z = xr1.z / d1; b.w = xr1.w / d1;
    *(float4*)&smem[buf * 1024 + u0 * 4] = a;
    *(float4*)&smem[buf * 1024 + u1 * 4] = b;
  };

  float ab[4][4], tt[4][4];
#pragma unroll
  for (int i = 0; i < 4; ++i)
#pragma unroll
    for (int j = 0; j < 4; ++j) ab[i][j] = 0.f;

  // prologue: stage chunk 0
  issueX(0);
  issueS(0, 0);
  writeX(0);  // compiler waits the two xr loads (vmcnt(4)), lds-loads stay in flight
  asm volatile("s_waitcnt vmcnt(0) lgkmcnt(0)" ::: "memory");
  __builtin_amdgcn_s_barrier();
  asm volatile("" ::: "memory");

  for (int ch = 0; ch < NCHUNK; ++ch) {
    const int buf = ch & 1;
    if (ch + 1 < NCHUNK) {
      issueX(ch + 1);           // 2 reg loads (oldest)
      issueS(buf ^ 1, ch + 1);  // 4 lds loads, in flight across compute
    }
    if (ch && (ch % KC_BLK) == 0) {  // kc=384 boundary: fold partial (FROZEN order)
#pragma unroll
      for (int i = 0; i < 4; ++i)
#pragma unroll
        for (int j = 0; j < 4; ++j) {
          if (ch == KC_BLK) tt[i][j] = ab[i][j];
          else tt[i][j] = __fadd_rn(tt[i][j], ab[i][j]);
          ab[i][j] = 0.f;
        }
    }

    const int xb = buf * 1024;
    const int sb = 2048 + buf * 2048;
#pragma unroll
    for (int u = 0; u < 8; ++u) {
      float4 xv[4], sv[4];
#pragma unroll
      for (int i = 0; i < 4; ++i) {
        const int row = rg * 4 + i;                 // (row>>2)&7 == rg
        xv[i] = *(const float4*)&smem[xb + row * 32 + ((u ^ rg) * 4)];
      }
#pragma unroll
      for (int j = 0; j < 4; ++j) {
        const int er = we * 32 + eg * 4 + j;        // (er>>2)&7 == eg (we*8 masked out)
        sv[j] = *(const float4*)&smem[sb + er * 32 + ((u ^ eg) * 4)];
      }
#pragma unroll
      for (int i = 0; i < 4; ++i)
#pragma unroll
        for (int j = 0; j < 4; ++j) {  // strict ascending-k fmaf chain (FROZEN)
          float a = ab[i][j];
          a = fmaf(xv[i].x, sv[j].x, a);
          a = fmaf(xv[i].y, sv[j].y, a);
          a = fmaf(xv[i].z, sv[j].z, a);
          a = fmaf(xv[i].w, sv[j].w, a);
          ab[i][j] = a;
        }
    }
    asm volatile("" ::: "memory");
    if (ch + 1 < NCHUNK) writeX(buf ^ 1);  // waits only the 2 xr loads
    asm volatile("s_waitcnt vmcnt(0) lgkmcnt(0)" ::: "memory");
    __builtin_amdgcn_s_barrier();
    asm volatile("" ::: "memory");
  }
#pragma unroll
  for (int i = 0; i < 4; ++i)
#pragma unroll
    for (int j = 0; j < 4; ++j) tt[i][j] = __fadd_rn(tt[i][j], ab[i][j]);  // tail 128

  // ---- epilogue: logits -> LDS transpose, then per-row wave ops ----
  float* lg = smem;  // [32][66], stride 66 => conflict-free row reads
#pragma unroll
  for (int i = 0; i < 4; ++i) {
    const int row = rg * 4 + i;
#pragma unroll
    for (int j = 0; j < 4; ++j) lg[row * 66 + we * 32 + eg * 4 + j] = tt[i][j];
  }
  __syncthreads();

  const int k = fbk[0];
  const float gate = gates[l];
  const size_t NE = (size_t)N * E_DIM;

  for (int rr = 0; rr < 16; ++rr) {
    const int row = we * 16 + rr;  // each wave owns 16 of the 32 rows; lane = expert
    const float logit = __fadd_rn(lg[row * 66 + l], -gate);
    const float gated = fmaxf(logit, 0.f);
    const bool act = logit > 0.f;
    const unsigned long long bal = __ballot(act);
    const bool inactive = (bal == 0ull);

    // top-k of raw logits (tie -> lowest index, matching lax.top_k)
    float cur = logit;
    bool fb = false;
    for (int tk = 0; tk < k; ++tk) {
      float v2 = cur;
      int idx = l;
#pragma unroll
      for (int off = 32; off >= 1; off >>= 1) {
        const float ov = __shfl_xor(v2, off);
        const int oi = __shfl_xor(idx, off);
        if (ov > v2 || (ov == v2 && oi < idx)) { v2 = ov; idx = oi; }
      }
      if (l == idx) { cur = -INFINITY; fb = true; }
    }

    const float mask = inactive ? (fb ? 1.f : 0.f) : (act ? 1.f : 0.f);
    const float masked = (mask > 0.f) ? gated : -INFINITY;
    float m = masked;
#pragma unroll
    for (int off = 32; off >= 1; off >>= 1) m = fmaxf(m, __shfl_xor(m, off));
    const float p = (mask > 0.f) ? expf(masked - m) : 0.f;
    float s = p;
#pragma unroll
    for (int off = 32; off >= 1; off >>= 1) s += __shfl_xor(s, off);
    const float wgt = p / s;

    const size_t gr = rowbase + row;
    out[gr * E_DIM + l] = wgt;             // routing_weights
    out[NE + gr * E_DIM + l] = logit;      // logits
    out[2 * NE + gr * E_DIM + l] = mask;   // activation_mask
  }
}

extern "C" void kernel_launch(void* const* d_in, const int* in_sizes, int n_in,
                              void* d_out, int out_size, void* d_ws, size_t ws_size,
                              hipStream_t stream) {
  (void)n_in; (void)out_size; (void)ws_size;
  const float* X = (const float*)d_in[0];
  const float* sim = (const float*)d_in[1];
  const float* gates = (const float*)d_in[2];
  const int* fbk = (const int*)d_in[3];
  float* out = (float*)d_out;
  float* den = (float*)d_ws;                       // 16384 fp32 = 64 KB
  float* sT = (float*)d_ws + 16384;                // 64*2048 fp32 = 512 KB
  float* Bsum = (float*)d_ws + 16384 + 131072;     // 16*64 fp32 = 4 KB
  const int N = in_sizes[0] / C_DIM;               // 16384

  hipLaunchKernelGGL(xnorm_kernel, dim3(N / 8), dim3(256), 0, stream, X, den, N);
  hipLaunchKernelGGL(simnorm_a_kernel, dim3(16), dim3(64), 0, stream, sim, Bsum);
  hipLaunchKernelGGL(simnorm_b_kernel, dim3(E_DIM), dim3(256), 0, stream, sim, Bsum, sT);
  hipLaunchKernelGGL(gating_main, dim3(N / 32), dim3(128), 0, stream, X, den, sT, gates, fbk, out, N);
}

// Round 9
// 328.551 us; speedup vs baseline: 2.2385x; 1.0751x over previous
//
#include <hip/hip_runtime.h>
#include <hip/hip_bf16.h>
#include <math.h>

#define C_DIM 2048
#define E_DIM 64
#define KC 32
#define ITERS 36           // critical-path chunks per k-group (g0: 36, g1: 28+8 idle)

typedef __attribute__((address_space(3))) float lds_f;
typedef const __attribute__((address_space(1))) float glb_f;

// ===========================================================================
// FROZEN ARITHMETIC (validated rounds 4 & 8, absmax 2.4e-4):
//  - norms: numpy pairwise tree; x*x rounded separately (__fmul_rn/__fadd_rn).
//  - normalize: IEEE fp32 divide per element.
//  - dot: per (row,expert) single fp32 acc, sequential fmaf ascending k,
//    kc=384 partials folded in order ((((p0+p1)+p2)+p3)+p4)+p5.
// Round 9: parallelize ACROSS kc-blocks (the 6 partial chains are independent;
// only the final fold is ordered) -> 2 k-groups x 2 expert-half waves = 8
// waves/CU (2/SIMD) at grid 512. Same LDS-port bytes, same HBM bytes.
// Round-5 lesson stands: no global loads inside the unrolled u-loop.
// ===========================================================================

// --------------------------- xnorm (unchanged) -----------------------------
__global__ __launch_bounds__(256) void xnorm_kernel(const float* __restrict__ X,
                                                    float* __restrict__ den, int N) {
  const int w = threadIdx.x >> 6, l = threadIdx.x & 63;
  const int row = blockIdx.x * 8 + w * 2 + (l >> 5);
  const int task = l & 31;
  const int b = task >> 1, a = (task & 1) * 4;
  const float* p0 = X + (size_t)row * C_DIM + b * 128 + a;

  float4 v = *(const float4*)p0;
  float ax = __fmul_rn(v.x, v.x), ay = __fmul_rn(v.y, v.y);
  float az = __fmul_rn(v.z, v.z), aw = __fmul_rn(v.w, v.w);
#pragma unroll
  for (int p = 1; p < 16; ++p) {
    v = *(const float4*)(p0 + p * 8);
    ax = __fadd_rn(ax, __fmul_rn(v.x, v.x));
    ay = __fadd_rn(ay, __fmul_rn(v.y, v.y));
    az = __fadd_rn(az, __fmul_rn(v.z, v.z));
    aw = __fadd_rn(aw, __fmul_rn(v.w, v.w));
  }
  float r = __fadd_rn(__fadd_rn(ax, ay), __fadd_rn(az, aw));
  r = __fadd_rn(r, __shfl_xor(r, 1));
  r = __fadd_rn(r, __shfl_xor(r, 2));
  r = __fadd_rn(r, __shfl_xor(r, 4));
  r = __fadd_rn(r, __shfl_xor(r, 8));
  r = __fadd_rn(r, __shfl_xor(r, 16));
  if (task == 0 && row < N) den[row] = fmaxf(sqrtf(r), 1e-12f);
}

// --------------------- simnorm a/b (unchanged) -----------------------------
__global__ __launch_bounds__(64) void simnorm_a_kernel(const float* __restrict__ sim,
                                                       float* __restrict__ Bsum) {
  const int b = blockIdx.x, l = threadIdx.x;
  const float* base = sim + (size_t)(b * 128) * E_DIM + l;
#define SQ(c) __fmul_rn(base[(c) * E_DIM], base[(c) * E_DIM])
  float a0 = SQ(0), a1 = SQ(1), a2 = SQ(2), a3 = SQ(3);
  float a4 = SQ(4), a5 = SQ(5), a6 = SQ(6), a7 = SQ(7);
#pragma unroll
  for (int g = 1; g < 16; ++g) {
    a0 = __fadd_rn(a0, SQ(g * 8 + 0)); a1 = __fadd_rn(a1, SQ(g * 8 + 1));
    a2 = __fadd_rn(a2, SQ(g * 8 + 2)); a3 = __fadd_rn(a3, SQ(g * 8 + 3));
    a4 = __fadd_rn(a4, SQ(g * 8 + 4)); a5 = __fadd_rn(a5, SQ(g * 8 + 5));
    a6 = __fadd_rn(a6, SQ(g * 8 + 6)); a7 = __fadd_rn(a7, SQ(g * 8 + 7));
  }
#undef SQ
  const float left = __fadd_rn(__fadd_rn(a0, a1), __fadd_rn(a2, a3));
  const float right = __fadd_rn(__fadd_rn(a4, a5), __fadd_rn(a6, a7));
  Bsum[b * E_DIM + l] = __fadd_rn(left, right);
}

__global__ __launch_bounds__(256) void simnorm_b_kernel(const float* __restrict__ sim,
                                                        const float* __restrict__ Bsum,
                                                        float* __restrict__ sT) {
  const int e = blockIdx.x, t = threadIdx.x;
  float B[16];
#pragma unroll
  for (int b = 0; b < 16; ++b) B[b] = Bsum[b * E_DIM + e];
  float c01 = __fadd_rn(B[0], B[1]), c23 = __fadd_rn(B[2], B[3]);
  float c45 = __fadd_rn(B[4], B[5]), c67 = __fadd_rn(B[6], B[7]);
  float c89 = __fadd_rn(B[8], B[9]), cab = __fadd_rn(B[10], B[11]);
  float ccd = __fadd_rn(B[12], B[13]), cef = __fadd_rn(B[14], B[15]);
  float q0 = __fadd_rn(c01, c23), q1 = __fadd_rn(c45, c67);
  float q2 = __fadd_rn(c89, cab), q3 = __fadd_rn(ccd, cef);
  const float tot = __fadd_rn(__fadd_rn(q0, q1), __fadd_rn(q2, q3));
  const float den = fmaxf(sqrtf(tot), 1e-12f);
#pragma unroll
  for (int i = 0; i < 8; ++i) {
    const int c = t + i * 256;
    sT[(size_t)e * C_DIM + c] = sim[(size_t)c * E_DIM + e] / den;
  }
}

// ---------------------------------------------------------------------------
// gating_main v4: 32 rows x 64 experts, 256 threads = 4 waves:
// wave = (k-half kh, expert-half we). Grid 512 -> 2 blocks/CU -> 8 waves/CU
// (2/SIMD, double r8's latency hiding). Each k-group owns a private
// double-buffered LDS region and stages only its own chunks (total port/HBM
// bytes unchanged). kh0: chunks 0..35 (p0,p1,p2 folded as prefix);
// kh1: chunks 36..63 (p3 in A, p4 in B, p5 in ab, kept separate).
// Merge folds ((((p0+p1)+p2)+p3)+p4)+p5 in the FROZEN order via LDS.
// ---------------------------------------------------------------------------
__global__ __launch_bounds__(256) void gating_main(const float* __restrict__ X,
                                                   const float* __restrict__ denx,
                                                   const float* __restrict__ sT,
                                                   const float* __restrict__ gates,
                                                   const int* __restrict__ fbk,
                                                   float* __restrict__ out, int N) {
  __shared__ float smem[12288];  // 48KB: X g0 [0,2048) g1 [2048,4096); sT g0 [4096,8192) g1 [8192,12288)
  const int t = threadIdx.x;
  const int w = t >> 6, l = t & 63;
  const int kh = w >> 1, we = w & 1;   // k-half x expert-half
  const int rg = l >> 3, eg = l & 7;   // 8 row-groups x 8 expert-groups
  const int tg = t & 127;              // thread id within k-group
  const size_t rowbase = (size_t)blockIdx.x * 32;
  const float* Xb = X + rowbase * C_DIM;

  const int XB = kh * 2048;            // my group's X dbuf base (floats)
  const int SB = 4096 + kh * 4096;     // my group's sT dbuf base
  const int KOFF = kh * 36;            // my group's first chunk
  const int LIM = kh ? 28 : 36;        // my group's chunk count

  // X staging: 256 units of 16B per group, 2/thread
  const int u0 = tg, u1 = tg + 128;
  const int r0 = u0 >> 3, cb0 = (u0 & 7) ^ ((r0 >> 2) & 7);
  const int r1 = u1 >> 3, cb1 = (u1 & 7) ^ ((r1 >> 2) & 7);
  const float d0 = denx[rowbase + r0];
  const float d1 = denx[rowbase + r1];
  const float* xg0 = Xb + (size_t)r0 * C_DIM + cb0 * 4;
  const float* xg1 = Xb + (size_t)r1 * C_DIM + cb1 * 4;

  // sT staging: 512 units per group, 4/thread (global_load_lds 16B)
  const float* sg[4];
  int sdst[4];
#pragma unroll
  for (int it = 0; it < 4; ++it) {
    const int v = tg + 128 * it;
    const int er = v >> 3, cb = (v & 7) ^ ((er >> 2) & 7);
    sg[it] = sT + (size_t)er * C_DIM + cb * 4;
    sdst[it] = SB + v * 4;  // + buf*2048 at issue
  }

  float4 xr0, xr1;
  auto issueX = [&](int ch) {
    xr0 = *(const float4*)(xg0 + ch * KC);
    xr1 = *(const float4*)(xg1 + ch * KC);
  };
  auto issueS = [&](int buf, int ch) {
#pragma unroll
    for (int it = 0; it < 4; ++it) {
      glb_f* g = (glb_f*)(sg[it] + ch * KC);
      lds_f* d = (lds_f*)&smem[sdst[it] + buf * 2048];
      __builtin_amdgcn_global_load_lds((const __attribute__((address_space(1))) void*)g,
                                       (__attribute__((address_space(3))) void*)d, 16, 0, 0);
    }
  };
  auto writeX = [&](int buf) {  // IEEE divide (FROZEN), then ds_write_b128
    float4 a, b;
    a.x = xr0.x / d0; a.y = xr0.y / d0; a.z = xr0.z / d0; a.w = xr0.w / d0;
    b.x = xr1.x / d1; b.y = xr1.y / d1; b.z = xr1.z / d1; b.w = xr1.w / d1;
    *(float4*)&smem[XB + buf * 1024 + u0 * 4] = a;
    *(float4*)&smem[XB + buf * 1024 + u1 * 4] = b;
  };

  // ab: running kc-block partial. A: g0 = fold prefix / g1 = p3. B: g1 = p4.
  float ab[4][4], A[4][4], B[4][4];
#pragma unroll
  for (int i = 0; i < 4; ++i)
#pragma unroll
    for (int j = 0; j < 4; ++j) { ab[i][j] = 0.f; A[i][j] = 0.f; B[i][j] = 0.f; }

  // prologue: stage my chunk 0 (valid for both groups)
  issueX(KOFF);
  issueS(0, KOFF);
  writeX(0);
  asm volatile("s_waitcnt vmcnt(0) lgkmcnt(0)" ::: "memory");
  __builtin_amdgcn_s_barrier();
  asm volatile("" ::: "memory");

  for (int it = 0; it < ITERS; ++it) {
    const int buf = it & 1;
    const bool nv = (it + 1) < LIM;  // next chunk valid for my group
    if (nv) {
      issueX(KOFF + it + 1);
      issueS(buf ^ 1, KOFF + it + 1);
    }
    if (it == 12) {  // kc boundary (g0: ch12, g1: ch48) — FROZEN fold points
#pragma unroll
      for (int i = 0; i < 4; ++i)
#pragma unroll
        for (int j = 0; j < 4; ++j) { A[i][j] = ab[i][j]; ab[i][j] = 0.f; }
    }
    if (it == 24) {  // g0: ch24 (fold into prefix), g1: ch60 (save p4)
#pragma unroll
      for (int i = 0; i < 4; ++i)
#pragma unroll
        for (int j = 0; j < 4; ++j) {
          if (kh == 0) A[i][j] = __fadd_rn(A[i][j], ab[i][j]);
          else B[i][j] = ab[i][j];
          ab[i][j] = 0.f;
        }
    }

    if (kh == 0 || it < 28) {  // compute my chunk from my group's buffers
      const int xb = XB + buf * 1024;
      const int sb = SB + buf * 2048;
#pragma unroll
      for (int u = 0; u < 8; ++u) {
        float4 xv[4], sv[4];
#pragma unroll
        for (int i = 0; i < 4; ++i) {
          const int row = rg * 4 + i;                 // (row>>2)&7 == rg
          xv[i] = *(const float4*)&smem[xb + row * 32 + ((u ^ rg) * 4)];
        }
#pragma unroll
        for (int j = 0; j < 4; ++j) {
          const int er = we * 32 + eg * 4 + j;        // (er>>2)&7 == eg
          sv[j] = *(const float4*)&smem[sb + er * 32 + ((u ^ eg) * 4)];
        }
#pragma unroll
        for (int i = 0; i < 4; ++i)
#pragma unroll
          for (int j = 0; j < 4; ++j) {  // strict ascending-k fmaf chain (FROZEN)
            float a = ab[i][j];
            a = fmaf(xv[i].x, sv[j].x, a);
            a = fmaf(xv[i].y, sv[j].y, a);
            a = fmaf(xv[i].z, sv[j].z, a);
            a = fmaf(xv[i].w, sv[j].w, a);
            ab[i][j] = a;
          }
      }
    }
    asm volatile("" ::: "memory");
    if (nv) writeX(buf ^ 1);
    asm volatile("s_waitcnt vmcnt(0) lgkmcnt(0)" ::: "memory");
    __builtin_amdgcn_s_barrier();
    asm volatile("" ::: "memory");
  }
  // tails: g0: fold p2 into prefix -> A = (p0+p1)+p2. g1: ab holds p5.
  if (kh == 0) {
#pragma unroll
    for (int i = 0; i < 4; ++i)
#pragma unroll
      for (int j = 0; j < 4; ++j) A[i][j] = __fadd_rn(A[i][j], ab[i][j]);
  }

  // ---- merge: g1 publishes p3,p4,p5; g0 folds in FROZEN order ----
  // P[b][32][66] at float offset b*2112 (b=0,1,2); lg at 6400
  if (kh == 1) {
#pragma unroll
    for (int i = 0; i < 4; ++i) {
      const int row = rg * 4 + i;
#pragma unroll
      for (int j = 0; j < 4; ++j) {
        const int e = we * 32 + eg * 4 + j;
        smem[row * 66 + e] = A[i][j];           // p3
        smem[2112 + row * 66 + e] = B[i][j];    // p4
        smem[4224 + row * 66 + e] = ab[i][j];   // p5
      }
    }
  }
  __syncthreads();
  float* lg = smem + 6400;  // [32][66]
  if (kh == 0) {
#pragma unroll
    for (int i = 0; i < 4; ++i) {
      const int row = rg * 4 + i;
#pragma unroll
      for (int j = 0; j < 4; ++j) {
        const int e = we * 32 + eg * 4 + j;
        float v = A[i][j];                               // (p0+p1)+p2
        v = __fadd_rn(v, smem[row * 66 + e]);            // +p3
        v = __fadd_rn(v, smem[2112 + row * 66 + e]);     // +p4
        v = __fadd_rn(v, smem[4224 + row * 66 + e]);     // +p5
        lg[row * 66 + e] = v;
      }
    }
  }
  __syncthreads();

  // ---- epilogue: 4 waves x 8 rows; lane = expert ----
  const int k = fbk[0];
  const float gate = gates[l];
  const size_t NE = (size_t)N * E_DIM;

  for (int rr = 0; rr < 8; ++rr) {
    const int row = w * 8 + rr;
    const float logit = __fadd_rn(lg[row * 66 + l], -gate);
    const float gated = fmaxf(logit, 0.f);
    const bool act = logit > 0.f;
    const unsigned long long bal = __ballot(act);
    const bool inactive = (bal == 0ull);

    // top-k of raw logits (tie -> lowest index, matching lax.top_k)
    float cur = logit;
    bool fb = false;
    for (int tk = 0; tk < k; ++tk) {
      float v2 = cur;
      int idx = l;
#pragma unroll
      for (int off = 32; off >= 1; off >>= 1) {
        const float ov = __shfl_xor(v2, off);
        const int oi = __shfl_xor(idx, off);
        if (ov > v2 || (ov == v2 && oi < idx)) { v2 = ov; idx = oi; }
      }
      if (l == idx) { cur = -INFINITY; fb = true; }
    }

    const float mask = inactive ? (fb ? 1.f : 0.f) : (act ? 1.f : 0.f);
    const float masked = (mask > 0.f) ? gated : -INFINITY;
    float m = masked;
#pragma unroll
    for (int off = 32; off >= 1; off >>= 1) m = fmaxf(m, __shfl_xor(m, off));
    const float p = (mask > 0.f) ? expf(masked - m) : 0.f;
    float s = p;
#pragma unroll
    for (int off = 32; off >= 1; off >>= 1) s += __shfl_xor(s, off);
    const float wgt = p / s;

    const size_t gr = rowbase + row;
    out[gr * E_DIM + l] = wgt;             // routing_weights
    out[NE + gr * E_DIM + l] = logit;      // logits
    out[2 * NE + gr * E_DIM + l] = mask;   // activation_mask
  }
}

extern "C" void kernel_launch(void* const* d_in, const int* in_sizes, int n_in,
                              void* d_out, int out_size, void* d_ws, size_t ws_size,
                              hipStream_t stream) {
  (void)n_in; (void)out_size; (void)ws_size;
  const float* X = (const float*)d_in[0];
  const float* sim = (const float*)d_in[1];
  const float* gates = (const float*)d_in[2];
  const int* fbk = (const int*)d_in[3];
  float* out = (float*)d_out;
  float* den = (float*)d_ws;                       // 16384 fp32 = 64 KB
  float* sT = (float*)d_ws + 16384;                // 64*2048 fp32 = 512 KB
  float* Bsum = (float*)d_ws + 16384 + 131072;     // 16*64 fp32 = 4 KB
  const int N = in_sizes[0] / C_DIM;               // 16384

  hipLaunchKernelGGL(xnorm_kernel, dim3(N / 8), dim3(256), 0, stream, X, den, N);
  hipLaunchKernelGGL(simnorm_a_kernel, dim3(16), dim3(64), 0, stream, sim, Bsum);
  hipLaunchKernelGGL(simnorm_b_kernel, dim3(E_DIM), dim3(256), 0, stream, sim, Bsum, sT);
  hipLaunchKernelGGL(gating_main, dim3(N / 32), dim3(256), 0, stream, X, den, sT, gates, fbk, out, N);
}